// Round 7
// baseline (69.689 us; speedup 1.0000x reference)
//
#include <hip/hip_runtime.h>
#include <math.h>

#define T_TOTAL 8192
#define D_TOTAL 4096
#define E 64
#define TOPK 8
#define NKB (D_TOTAL / 32)      // 128 k-blocks of 32

#define S_SPLIT 16              // K-split across blockIdx.y
#define KCH (D_TOTAL / S_SPLIT) // 256 k per block
#define KB_PER_BLK (KCH / 32)   // 8
#define TOKW 16                 // tokens per wave
#define WVS 16                  // waves per block
#define TOKB (TOKW * WVS)       // 256 tokens per block
#define CHUNK8 (KB_PER_BLK * 4 * 64)   // 2048 short8 per split-array per block

typedef short short8 __attribute__((ext_vector_type(8)));
typedef float f32x4 __attribute__((ext_vector_type(4)));

// scalar split (prep kernel)
__device__ __forceinline__ void split3(const float* v8, short8& h, short8& m, short8& l) {
#pragma unroll
    for (int j = 0; j < 8; ++j) {
        const float f = v8[j];
        const unsigned u = __float_as_uint(f);
        const unsigned hu = u & 0xffff0000u;
        const float r1 = f - __uint_as_float(hu);
        const unsigned mu = __float_as_uint(r1) & 0xffff0000u;
        const float r2 = r1 - __uint_as_float(mu);
        const unsigned lu = __float_as_uint(r2);
        h[j] = (short)(hu >> 16);
        m[j] = (short)(mu >> 16);
        l[j] = (short)(lu >> 16);
    }
}

// v_perm-based split for the hot kernel: pack 2 bf16 per op
__device__ __forceinline__ void split3v(const float* v, short8& h, short8& m, short8& l) {
    unsigned* hp = reinterpret_cast<unsigned*>(&h);
    unsigned* mp = reinterpret_cast<unsigned*>(&m);
    unsigned* lp = reinterpret_cast<unsigned*>(&l);
#pragma unroll
    for (int p = 0; p < 4; ++p) {
        const float a = v[2 * p], b = v[2 * p + 1];
        const unsigned hw = __builtin_amdgcn_perm(__float_as_uint(b), __float_as_uint(a), 0x07060302u);
        const float r0 = a - __uint_as_float(hw << 16);
        const float r1 = b - __uint_as_float(hw & 0xffff0000u);
        const unsigned mw = __builtin_amdgcn_perm(__float_as_uint(r1), __float_as_uint(r0), 0x07060302u);
        const float s0 = r0 - __uint_as_float(mw << 16);
        const float s1 = r1 - __uint_as_float(mw & 0xffff0000u);
        const unsigned lw = __builtin_amdgcn_perm(__float_as_uint(s1), __float_as_uint(s0), 0x07060302u);
        hp[p] = hw; mp[p] = mw; lp[p] = lw;
    }
}

// ---------------- Prep: w -> frag-ordered bf16 split arrays ----------------
// index: (kb*4 + nt)*64 + lane ; element j holds w[e][k+j]
__global__ __launch_bounds__(256)
void prep_w(const float* __restrict__ w, short8* __restrict__ Bh,
            short8* __restrict__ Bm, short8* __restrict__ Bl) {
    const int t = blockIdx.x * 256 + threadIdx.x;   // [0, NKB*4*64)
    const int lane = t & 63;
    const int nt = (t >> 6) & 3;
    const int kb = t >> 8;
    const int e = nt * 16 + (lane & 15);
    const int k = kb * 32 + (lane >> 4) * 8;

    const float* src = w + (size_t)e * D_TOTAL + k;
    float v[8];
    *reinterpret_cast<float4*>(&v[0]) = *reinterpret_cast<const float4*>(src);
    *reinterpret_cast<float4*>(&v[4]) = *reinterpret_cast<const float4*>(src + 4);

    short8 h, m, l;
    split3(v, h, m, l);
    Bh[t] = h; Bm[t] = m; Bl[t] = l;
}

// ---------------- GEMM: B staged in LDS, S=16 K-split across blocks ----------
// grid (32, 16): x = 256-token strip, y = K-chunk. 16 waves x 16 tokens.
// LDS 96 KB -> 1 block/CU, 4 waves/SIMD, VGPR cap 128.
__global__ __launch_bounds__(1024, 4)
void gemm_lds(const float* __restrict__ x,
              const short8* __restrict__ Bh, const short8* __restrict__ Bm,
              const short8* __restrict__ Bl,
              float* __restrict__ part) {
    __shared__ short8 Bs[3 * CHUNK8];   // 96 KB

    const int tid = threadIdx.x;
    const int lane = tid & 63;
    const int wv = tid >> 6;
    const int s = blockIdx.y;
    const int tok0 = blockIdx.x * TOKB + wv * TOKW;

    // ---- stage B chunk: 6144 short8, 6 per thread, coalesced ----
    {
        const short8* g0 = Bh + (size_t)s * CHUNK8;
        const short8* g1 = Bm + (size_t)s * CHUNK8;
        const short8* g2 = Bl + (size_t)s * CHUNK8;
#pragma unroll
        for (int t = 0; t < 6; ++t) {
            const int j = t * 1024 + tid;
            const int a = j >> 11;          // 0..2
            const int idx = j & (CHUNK8 - 1);
            const short8* g = (a == 0) ? g0 : (a == 1) ? g1 : g2;
            Bs[j] = g[idx];
        }
    }

    const int row = lane & 15;
    const int kq = lane >> 4;
    const float* xb = x + (size_t)(tok0 + row) * D_TOTAL + s * KCH + kq * 8;

    f32x4 acc[4];
#pragma unroll
    for (int n = 0; n < 4; ++n) acc[n] = (f32x4){0.f, 0.f, 0.f, 0.f};

    // x prefetch, distance 2 (statically indexed ring of 3)
    float xr[3][8];
#pragma unroll
    for (int p = 0; p < 2; ++p) {
        const float* ap = xb + p * 32;
        *reinterpret_cast<float4*>(&xr[p][0]) = *reinterpret_cast<const float4*>(ap);
        *reinterpret_cast<float4*>(&xr[p][4]) = *reinterpret_cast<const float4*>(ap + 4);
    }

    __syncthreads();   // B staged

#pragma unroll
    for (int kb = 0; kb < KB_PER_BLK; ++kb) {
        if (kb < KB_PER_BLK - 2) {
            const float* ap = xb + (kb + 2) * 32;
            *reinterpret_cast<float4*>(&xr[(kb + 2) % 3][0]) = *reinterpret_cast<const float4*>(ap);
            *reinterpret_cast<float4*>(&xr[(kb + 2) % 3][4]) = *reinterpret_cast<const float4*>(ap + 4);
        }

        short8 ah, am_, al;
        split3v(xr[kb % 3], ah, am_, al);

        // B fragments from LDS (12 x ds_read_b128)
        short8 bh[4], bm[4], bl[4];
#pragma unroll
        for (int nt = 0; nt < 4; ++nt) {
            const int bi = (kb * 4 + nt) * 64 + lane;
            bh[nt] = Bs[bi];
            bm[nt] = Bs[CHUNK8 + bi];
            bl[nt] = Bs[2 * CHUNK8 + bi];
        }

#pragma unroll
        for (int nt = 0; nt < 4; ++nt) {
            f32x4 c = acc[nt];
            c = __builtin_amdgcn_mfma_f32_16x16x32_bf16(ah,  bh[nt], c, 0, 0, 0);
            c = __builtin_amdgcn_mfma_f32_16x16x32_bf16(ah,  bm[nt], c, 0, 0, 0);
            c = __builtin_amdgcn_mfma_f32_16x16x32_bf16(am_, bh[nt], c, 0, 0, 0);
            c = __builtin_amdgcn_mfma_f32_16x16x32_bf16(am_, bm[nt], c, 0, 0, 0);
            c = __builtin_amdgcn_mfma_f32_16x16x32_bf16(ah,  bl[nt], c, 0, 0, 0);
            c = __builtin_amdgcn_mfma_f32_16x16x32_bf16(al,  bh[nt], c, 0, 0, 0);
            acc[nt] = c;
        }
    }

    // partial write: part[s][tok][e]; C/D: col=lane&15, row=(lane>>4)*4+r
    float* pb = part + ((size_t)s * T_TOTAL + tok0) * E;
#pragma unroll
    for (int nt = 0; nt < 4; ++nt) {
        const int e = nt * 16 + (lane & 15);
#pragma unroll
        for (int r = 0; r < 4; ++r) {
            const int t = (lane >> 4) * 4 + r;
            pb[(size_t)t * E + e] = acc[nt][r];
        }
    }
}

// ---------------- sum partials + sigmoid + top-8 ----------------
__global__ __launch_bounds__(256)
void topk_kernel(const float* __restrict__ part, float* __restrict__ out) {
    __shared__ float fin[32 * 64];

    const int tid = threadIdx.x;
    const int tok0 = blockIdx.x * 32;
    const size_t base = (size_t)tok0 * E;

    const int f = tid * 8;
    float4 v0 = make_float4(0.f, 0.f, 0.f, 0.f);
    float4 v1 = make_float4(0.f, 0.f, 0.f, 0.f);
#pragma unroll
    for (int s = 0; s < S_SPLIT; ++s) {
        const float4* p = reinterpret_cast<const float4*>(
            part + (size_t)s * T_TOTAL * E + base + f);
        const float4 a = p[0];
        const float4 b = p[1];
        v0.x += a.x; v0.y += a.y; v0.z += a.z; v0.w += a.w;
        v1.x += b.x; v1.y += b.y; v1.z += b.z; v1.w += b.w;
    }
    *reinterpret_cast<float4*>(&fin[f]) = v0;
    *reinterpret_cast<float4*>(&fin[f + 4]) = v1;
    __syncthreads();

    // 4 waves x 8 tokens each, lane = expert
    const int lane = tid & 63;
    const int wv = tid >> 6;
#pragma unroll
    for (int rep = 0; rep < 8; ++rep) {
        const int t = wv * 8 + rep;
        float v = fin[t * 64 + lane];
        float wj[TOPK];
        int   ij[TOPK];
        float wsum = 0.f;
#pragma unroll
        for (int j = 0; j < TOPK; ++j) {
            float mx = v;
#pragma unroll
            for (int off = 32; off >= 1; off >>= 1)
                mx = fmaxf(mx, __shfl_xor(mx, off));
            const unsigned long long msk = __ballot(v == mx);
            const int widx = (int)__builtin_ctzll(msk);   // lowest index on ties
            wj[j] = 1.f / (1.f + expf(-mx));
            ij[j] = widx;
            wsum += wj[j];
            if (lane == widx) v = -INFINITY;
        }
        const float inv = 1.f / fmaxf(wsum, 1e-12f);
        const int tg = tok0 + t;
        if (lane == 0) {
#pragma unroll
            for (int j = 0; j < TOPK; ++j)
                out[(size_t)tg * TOPK + j] = wj[j] * inv;
#pragma unroll
            for (int j = 0; j < TOPK; ++j)
                out[(size_t)T_TOTAL * TOPK + (size_t)tg * TOPK + j] = (float)ij[j];
        }
    }
}

extern "C" void kernel_launch(void* const* d_in, const int* in_sizes, int n_in,
                              void* d_out, int out_size, void* d_ws, size_t ws_size,
                              hipStream_t stream) {
    const float* x = (const float*)d_in[0];
    const float* w = (const float*)d_in[1];
    float* out = (float*)d_out;

    float* part = (float*)d_ws;   // 16 * 8192 * 64 * 4 = 32 MB
    short8* Bh = (short8*)((char*)d_ws + (size_t)S_SPLIT * T_TOTAL * E * sizeof(float));
    short8* Bm = Bh + (size_t)NKB * 4 * 64;
    short8* Bl = Bm + (size_t)NKB * 4 * 64;

    prep_w<<<NKB * 4 * 64 / 256, 256, 0, stream>>>(w, Bh, Bm, Bl);
    dim3 g(T_TOTAL / TOKB, S_SPLIT);
    gemm_lds<<<g, 1024, 0, stream>>>(x, Bh, Bm, Bl, part);
    topk_kernel<<<T_TOTAL / 32, 256, 0, stream>>>(part, out);
}

// Round 8
// 53.362 us; speedup vs baseline: 1.3060x; 1.3060x over previous
//
#include <hip/hip_runtime.h>
#include <math.h>

#define T_TOTAL 8192
#define D_TOTAL 4096
#define E 64
#define TOPK 8
#define NKB (D_TOTAL / 32)      // 128 k-blocks of 32

#define WVS 8                    // waves per block
#define WKCH (D_TOTAL / WVS)     // 512 k per wave -> 16 kb
#define TOKB 32                  // tokens per block (M2 per wave)

typedef short short8 __attribute__((ext_vector_type(8)));
typedef float f32x4 __attribute__((ext_vector_type(4)));

// scalar split (prep kernel)
__device__ __forceinline__ void split3(const float* v8, short8& h, short8& m, short8& l) {
#pragma unroll
    for (int j = 0; j < 8; ++j) {
        const float f = v8[j];
        const unsigned u = __float_as_uint(f);
        const unsigned hu = u & 0xffff0000u;
        const float r1 = f - __uint_as_float(hu);
        const unsigned mu = __float_as_uint(r1) & 0xffff0000u;
        const float r2 = r1 - __uint_as_float(mu);
        const unsigned lu = __float_as_uint(r2);
        h[j] = (short)(hu >> 16);
        m[j] = (short)(mu >> 16);
        l[j] = (short)(lu >> 16);
    }
}

// v_perm-based split: pack 2 bf16 per op
__device__ __forceinline__ void split3v(const float* v, short8& h, short8& m, short8& l) {
    unsigned* hp = reinterpret_cast<unsigned*>(&h);
    unsigned* mp = reinterpret_cast<unsigned*>(&m);
    unsigned* lp = reinterpret_cast<unsigned*>(&l);
#pragma unroll
    for (int p = 0; p < 4; ++p) {
        const float a = v[2 * p], b = v[2 * p + 1];
        const unsigned hw = __builtin_amdgcn_perm(__float_as_uint(b), __float_as_uint(a), 0x07060302u);
        const float r0 = a - __uint_as_float(hw << 16);
        const float r1 = b - __uint_as_float(hw & 0xffff0000u);
        const unsigned mw = __builtin_amdgcn_perm(__float_as_uint(r1), __float_as_uint(r0), 0x07060302u);
        const float s0 = r0 - __uint_as_float(mw << 16);
        const float s1 = r1 - __uint_as_float(mw & 0xffff0000u);
        const unsigned lw = __builtin_amdgcn_perm(__float_as_uint(s1), __float_as_uint(s0), 0x07060302u);
        hp[p] = hw; mp[p] = mw; lp[p] = lw;
    }
}

// ---------------- Prep: w -> frag-ordered bf16 split arrays ----------------
// index: (gkb*4 + nt)*64 + lane ; element j holds w[e][k+j]
__global__ __launch_bounds__(256)
void prep_w(const float* __restrict__ w, short8* __restrict__ Bh,
            short8* __restrict__ Bm, short8* __restrict__ Bl) {
    const int t = blockIdx.x * 256 + threadIdx.x;   // [0, NKB*4*64)
    const int lane = t & 63;
    const int nt = (t >> 6) & 3;
    const int kb = t >> 8;
    const int e = nt * 16 + (lane & 15);
    const int k = kb * 32 + (lane >> 4) * 8;

    const float* src = w + (size_t)e * D_TOTAL + k;
    float v[8];
    *reinterpret_cast<float4*>(&v[0]) = *reinterpret_cast<const float4*>(src);
    *reinterpret_cast<float4*>(&v[4]) = *reinterpret_cast<const float4*>(src + 4);

    short8 h, m, l;
    split3(v, h, m, l);
    Bh[t] = h; Bm[t] = m; Bl[t] = l;
}

// ---------------- Fused: 8 waves x (32 tok M2, K-chunk 512), in-block topk ----
// grid 256 = 2 blocks/CU. Batched 12 B-loads per kb, x ring-2 prefetch.
__global__ __launch_bounds__(512, 4)
void fused_router(const float* __restrict__ x,
                  const short8* __restrict__ Bh, const short8* __restrict__ Bm,
                  const short8* __restrict__ Bl,
                  float* __restrict__ out) {
    __shared__ float tiles[4][2048];   // 32 KB
    __shared__ float fin[2048];        // 8 KB

    const int tid = threadIdx.x;
    const int lane = tid & 63;
    const int wv = tid >> 6;
    const int tok0 = blockIdx.x * TOKB;

    const int row = lane & 15;
    const int kq = lane >> 4;
    const float* xb = x + (size_t)(tok0 + row) * D_TOTAL + wv * WKCH + kq * 8;

    f32x4 acc[2][4];
#pragma unroll
    for (int m = 0; m < 2; ++m)
#pragma unroll
        for (int n = 0; n < 4; ++n) acc[m][n] = (f32x4){0.f, 0.f, 0.f, 0.f};

    float xr[2][2][8];   // [buf][m][8]
#pragma unroll
    for (int m = 0; m < 2; ++m) {
        const float* ap = xb + (size_t)(m * 16) * D_TOTAL;
        *reinterpret_cast<float4*>(&xr[0][m][0]) = *reinterpret_cast<const float4*>(ap);
        *reinterpret_cast<float4*>(&xr[0][m][4]) = *reinterpret_cast<const float4*>(ap + 4);
    }

#pragma unroll
    for (int kb = 0; kb < 16; ++kb) {
        const int gkb = wv * 16 + kb;

        // ---- batched B fragment loads (12 x dwordx4, independent) ----
        short8 bh[4], bm_[4], bl[4];
#pragma unroll
        for (int nt = 0; nt < 4; ++nt) {
            const size_t bi = (size_t)(gkb * 4 + nt) * 64 + lane;
            bh[nt]  = Bh[bi];
            bm_[nt] = Bm[bi];
            bl[nt]  = Bl[bi];
        }

        // ---- x prefetch next kb (ring-2) ----
        if (kb < 15) {
#pragma unroll
            for (int m = 0; m < 2; ++m) {
                const float* ap = xb + (size_t)(m * 16) * D_TOTAL + (kb + 1) * 32;
                *reinterpret_cast<float4*>(&xr[(kb + 1) & 1][m][0]) = *reinterpret_cast<const float4*>(ap);
                *reinterpret_cast<float4*>(&xr[(kb + 1) & 1][m][4]) = *reinterpret_cast<const float4*>(ap + 4);
            }
        }

        // ---- compute: term-outer, nt-inner (4 independent acc chains) ----
#pragma unroll
        for (int m = 0; m < 2; ++m) {
            short8 ah, am_, al;
            split3v(xr[kb & 1][m], ah, am_, al);
#pragma unroll
            for (int nt = 0; nt < 4; ++nt) acc[m][nt] = __builtin_amdgcn_mfma_f32_16x16x32_bf16(ah,  bh[nt],  acc[m][nt], 0, 0, 0);
#pragma unroll
            for (int nt = 0; nt < 4; ++nt) acc[m][nt] = __builtin_amdgcn_mfma_f32_16x16x32_bf16(ah,  bm_[nt], acc[m][nt], 0, 0, 0);
#pragma unroll
            for (int nt = 0; nt < 4; ++nt) acc[m][nt] = __builtin_amdgcn_mfma_f32_16x16x32_bf16(am_, bh[nt],  acc[m][nt], 0, 0, 0);
#pragma unroll
            for (int nt = 0; nt < 4; ++nt) acc[m][nt] = __builtin_amdgcn_mfma_f32_16x16x32_bf16(am_, bm_[nt], acc[m][nt], 0, 0, 0);
#pragma unroll
            for (int nt = 0; nt < 4; ++nt) acc[m][nt] = __builtin_amdgcn_mfma_f32_16x16x32_bf16(ah,  bl[nt],  acc[m][nt], 0, 0, 0);
#pragma unroll
            for (int nt = 0; nt < 4; ++nt) acc[m][nt] = __builtin_amdgcn_mfma_f32_16x16x32_bf16(al,  bh[nt],  acc[m][nt], 0, 0, 0);
        }
    }

    // ---- reduce 8 wave-partials: waves 4-7 store, 0-3 add, then flat sum ----
    // tile layout: [j = m*16 + nt*4 + r][lane]
    if (wv >= 4) {
        float* s = &tiles[wv - 4][lane];
#pragma unroll
        for (int m = 0; m < 2; ++m)
#pragma unroll
            for (int nt = 0; nt < 4; ++nt)
#pragma unroll
                for (int r = 0; r < 4; ++r)
                    s[(m * 16 + nt * 4 + r) * 64] = acc[m][nt][r];
    }
    __syncthreads();
    if (wv < 4) {
        float* s = &tiles[wv][lane];
#pragma unroll
        for (int m = 0; m < 2; ++m)
#pragma unroll
            for (int nt = 0; nt < 4; ++nt)
#pragma unroll
                for (int r = 0; r < 4; ++r) {
                    const int j = (m * 16 + nt * 4 + r) * 64;
                    s[j] = acc[m][nt][r] + s[j];
                }
    }
    __syncthreads();

    // flat sum over 4 tiles; thread owns j4 = tid + p*512, p=0..3
#pragma unroll
    for (int p = 0; p < 4; ++p) {
        const int j4 = tid + p * 512;
        float s0 = tiles[0][j4] + tiles[1][j4];
        s0 += tiles[2][j4] + tiles[3][j4];
        const int j = j4 >> 6, ln = j4 & 63;
        const int t = (j >> 4) * 16 + (ln >> 4) * 4 + (j & 3);
        const int e = ((j >> 2) & 3) * 16 + (ln & 15);
        fin[t * 64 + e] = s0;
    }
    __syncthreads();

    // ---- per-wave top-8: wave wv handles tokens wv*4 .. wv*4+3 ----
#pragma unroll
    for (int rep = 0; rep < 4; ++rep) {
        const int t = wv * 4 + rep;
        float v = fin[t * 64 + lane];
        float wj[TOPK];
        int   ij[TOPK];
        float wsum = 0.f;
#pragma unroll
        for (int j = 0; j < TOPK; ++j) {
            float mx = v;
#pragma unroll
            for (int off = 32; off >= 1; off >>= 1)
                mx = fmaxf(mx, __shfl_xor(mx, off));
            const unsigned long long msk = __ballot(v == mx);
            const int widx = (int)__builtin_ctzll(msk);   // lowest index on ties (stable)
            wj[j] = 1.f / (1.f + expf(-mx));
            ij[j] = widx;
            wsum += wj[j];
            if (lane == widx) v = -INFINITY;
        }
        const float inv = 1.f / fmaxf(wsum, 1e-12f);
        const int tg = tok0 + t;
        if (lane == 0) {
#pragma unroll
            for (int j = 0; j < TOPK; ++j)
                out[(size_t)tg * TOPK + j] = wj[j] * inv;
#pragma unroll
            for (int j = 0; j < TOPK; ++j)
                out[(size_t)T_TOTAL * TOPK + (size_t)tg * TOPK + j] = (float)ij[j];
        }
    }
}

extern "C" void kernel_launch(void* const* d_in, const int* in_sizes, int n_in,
                              void* d_out, int out_size, void* d_ws, size_t ws_size,
                              hipStream_t stream) {
    const float* x = (const float*)d_in[0];
    const float* w = (const float*)d_in[1];
    float* out = (float*)d_out;

    short8* Bh = (short8*)d_ws;
    short8* Bm = Bh + (size_t)NKB * 4 * 64;
    short8* Bl = Bm + (size_t)NKB * 4 * 64;

    prep_w<<<NKB * 4 * 64 / 256, 256, 0, stream>>>(w, Bh, Bm, Bl);
    fused_router<<<T_TOTAL / TOKB, 512, 0, stream>>>(x, Bh, Bm, Bl, out);
}